// Round 1
// baseline (212.902 us; speedup 1.0000x reference)
//
#include <hip/hip_runtime.h>

// Problem constants: (B, C, H, W) = (32, 3, 512, 512), fp32.
#define HW_PLANE (512 * 512)          // 262144, pow2 -> shift 18
#define NPIX     (32 * HW_PLANE)      // 8,388,608 pixels total
#define NBLOCKS  1024

// Hue of one RGB pixel, matching the jnp reference exactly:
//   maxc==r branch first, then maxc==g, else b-branch; h/6 % 1.0 (Python mod);
//   delta==0 -> 0.
__device__ __forceinline__ float hue1(float r, float g, float b) {
    float maxc  = fmaxf(r, fmaxf(g, b));
    float minc  = fminf(r, fminf(g, b));
    float delta = maxc - minc;
    float safe  = (delta == 0.0f) ? 1.0f : delta;
    float h;
    if (maxc == r)      h = (g - b) / safe;
    else if (maxc == g) h = 2.0f + (b - r) / safe;
    else                h = 4.0f + (r - g) / safe;
    h = h * (1.0f / 6.0f);
    h = h - floorf(h);                 // Python % 1.0 (result in [0,1) incl. negatives)
    return (delta == 0.0f) ? 0.0f : h;
}

__device__ __forceinline__ void acc_diff(float hp, float ht, float& lo, float& hi) {
    float d = fabsf(hp - ht);
    // mask_ = d < 0.5 ; mask = d > 0.5 ; d == 0.5 contributes to neither.
    if (d < 0.5f)      lo += d;
    else if (d > 0.5f) hi += d - 0.5f; // |(d-0.5)*mask| == d-0.5 since d>0.5
}

__global__ void __launch_bounds__(256)
hsv_partial(const float* __restrict__ pred, const float* __restrict__ targ,
            float2* __restrict__ partial) {
    const int tid    = blockIdx.x * blockDim.x + threadIdx.x;
    const int stride = gridDim.x * blockDim.x;
    const int N4     = NPIX / 4;       // one float4 (4 pixels) per iteration

    float lo = 0.0f, hi = 0.0f;
    for (int i = tid; i < N4; i += stride) {
        int p    = i << 2;             // pixel index
        int bimg = p >> 18;            // p / HW_PLANE
        int pix  = p & (HW_PLANE - 1); // p % HW_PLANE
        int base = bimg * (3 * HW_PLANE) + pix;

        float4 pr = *(const float4*)(pred + base);
        float4 pg = *(const float4*)(pred + base + HW_PLANE);
        float4 pb = *(const float4*)(pred + base + 2 * HW_PLANE);
        float4 tr = *(const float4*)(targ + base);
        float4 tg = *(const float4*)(targ + base + HW_PLANE);
        float4 tb = *(const float4*)(targ + base + 2 * HW_PLANE);

        acc_diff(hue1(pr.x, pg.x, pb.x), hue1(tr.x, tg.x, tb.x), lo, hi);
        acc_diff(hue1(pr.y, pg.y, pb.y), hue1(tr.y, tg.y, tb.y), lo, hi);
        acc_diff(hue1(pr.z, pg.z, pb.z), hue1(tr.z, tg.z, tb.z), lo, hi);
        acc_diff(hue1(pr.w, pg.w, pb.w), hue1(tr.w, tg.w, tb.w), lo, hi);
    }

    // wave (64-lane) shuffle reduction
    for (int off = 32; off > 0; off >>= 1) {
        lo += __shfl_down(lo, off, 64);
        hi += __shfl_down(hi, off, 64);
    }
    __shared__ float slo[4], shi[4];   // 256 threads = 4 waves
    int lane = threadIdx.x & 63;
    int wave = threadIdx.x >> 6;
    if (lane == 0) { slo[wave] = lo; shi[wave] = hi; }
    __syncthreads();
    if (threadIdx.x == 0) {
        partial[blockIdx.x] =
            make_float2(slo[0] + slo[1] + slo[2] + slo[3],
                        shi[0] + shi[1] + shi[2] + shi[3]);
    }
}

__global__ void __launch_bounds__(256)
hsv_final(const float2* __restrict__ partial, float* __restrict__ out) {
    float lo = 0.0f, hi = 0.0f;
    for (int i = threadIdx.x; i < NBLOCKS; i += blockDim.x) {
        float2 p = partial[i];
        lo += p.x; hi += p.y;
    }
    for (int off = 32; off > 0; off >>= 1) {
        lo += __shfl_down(lo, off, 64);
        hi += __shfl_down(hi, off, 64);
    }
    __shared__ float slo[4], shi[4];
    int lane = threadIdx.x & 63;
    int wave = threadIdx.x >> 6;
    if (lane == 0) { slo[wave] = lo; shi[wave] = hi; }
    __syncthreads();
    if (threadIdx.x == 0) {
        float L = slo[0] + slo[1] + slo[2] + slo[3];
        float H = shi[0] + shi[1] + shi[2] + shi[3];
        out[0] = (L + H) * (1.0f / (float)NPIX);   // mean_lo + mean_hi, same N
    }
}

extern "C" void kernel_launch(void* const* d_in, const int* in_sizes, int n_in,
                              void* d_out, int out_size, void* d_ws, size_t ws_size,
                              hipStream_t stream) {
    const float* pred = (const float*)d_in[0];
    const float* targ = (const float*)d_in[1];
    float*  out     = (float*)d_out;
    float2* partial = (float2*)d_ws;   // NBLOCKS * 8 B = 8 KiB scratch

    hsv_partial<<<NBLOCKS, 256, 0, stream>>>(pred, targ, partial);
    hsv_final<<<1, 256, 0, stream>>>(partial, out);
}